// Round 1
// baseline (548.034 us; speedup 1.0000x reference)
//
#include <hip/hip_runtime.h>
#include <hip/hip_bf16.h>

// GPT2 symmetric latent attention, MI355X (gfx950)
// B=4 T=2048 C=1024 H=16 R=64 head_dim=64
//
// Pipeline:
//  1. cvt f32->bf16: hs, basis_w, v_w, o_w
//  2. head_mats: hmT[h][s][r] = core_sym[r][s]/H + centered resid (bf16)
//  3. latent = hs @ basis^T            (MFMA NT gemm, 8192x64, K=1024)
//  4. v      = hs @ v_w^T + v_b        (8192x1024, K=1024)
//  5. lt     = latent @ hmT^T batched  (per (b,h): 2048x64, K=64)
//  6. flash attention: S = lt@latent^T /8, causal softmax, O = P@V -> y bf16
//  7. out    = y @ o_w^T + o_b (f32)

#define N_HEAD 16
#define RANK 64

typedef __attribute__((ext_vector_type(8))) short bf16x8;
typedef __attribute__((ext_vector_type(4))) float f32x4;

__device__ __forceinline__ ushort f2b(float f) {
    // round-to-nearest-even f32 -> bf16
    unsigned u = __builtin_bit_cast(unsigned, f);
    u += 0x7fffu + ((u >> 16) & 1u);
    return (ushort)(u >> 16);
}

__global__ void cvt_kernel(const float* __restrict__ src, ushort* __restrict__ dst, int n4) {
    int i = blockIdx.x * blockDim.x + threadIdx.x;
    if (i >= n4) return;
    float4 v = ((const float4*)src)[i];
    ushort4 o;
    o.x = f2b(v.x); o.y = f2b(v.y); o.z = f2b(v.z); o.w = f2b(v.w);
    ((ushort4*)dst)[i] = o;
}

// head_mats^T in bf16: hmT[h][s][r] = core_sym[r][s]/H + (resid[h][r][s] - mean_h resid[.][r][s])
__global__ void headmats_kernel(const float* __restrict__ core,
                                const float* __restrict__ resid,
                                ushort* __restrict__ hmT) {
    int idx = blockIdx.x * 256 + threadIdx.x;  // (r,s) flat, 4096 total
    if (idx >= RANK * RANK) return;
    int r = idx >> 6, s = idx & 63;
    float mean = 0.f;
    for (int h = 0; h < N_HEAD; ++h) mean += resid[h * RANK * RANK + idx];
    mean *= (1.0f / N_HEAD);
    float cs = 0.5f * (core[r * RANK + s] + core[s * RANK + r]) * (1.0f / N_HEAD);
    for (int h = 0; h < N_HEAD; ++h) {
        float val = cs + resid[h * RANK * RANK + idx] - mean;
        hmT[h * RANK * RANK + s * RANK + r] = f2b(val);
    }
}

// Generic NT GEMM: C[m,n] = sum_k A[m,k] * W[n,k] (+bias[n]).
// A,W bf16 row-major; out f32 and/or bf16. 128x64 tile, BK=64, 4 waves (2x2).
// Batched via blockIdx.z: A += (z/zDivA)*aStride, W += (z%zModW)*wStride, out += z*oStride.
__global__ __launch_bounds__(256) void gemm_nt(
    const ushort* __restrict__ A, const ushort* __restrict__ W,
    const float* __restrict__ bias,
    float* __restrict__ outF, ushort* __restrict__ outB,
    int M, int N, int K,
    int zDivA, long long aStride, int zModW, long long wStride, long long oStride)
{
    __shared__ ushort As[128 * 72];  // +8 pad: 144B row stride -> 2-way bank alias (free)
    __shared__ ushort Ws[64 * 72];

    int z = blockIdx.z;
    A += (size_t)(z / zDivA) * aStride;
    W += (size_t)(z % zModW) * wStride;
    size_t obase = (size_t)z * oStride;

    int m0 = blockIdx.y * 128;
    int n0 = blockIdx.x * 64;
    int t = threadIdx.x;
    int wave = t >> 6, lane = t & 63;
    int wr = wave >> 1, wc = wave & 1;  // wave computes rows wr*64..+64, cols wc*32..+32
    int g = lane >> 4, ln = lane & 15;

    f32x4 acc[4][2];
    for (int i = 0; i < 4; ++i)
        for (int j = 0; j < 2; ++j) acc[i][j] = (f32x4){0.f, 0.f, 0.f, 0.f};

    for (int k0 = 0; k0 < K; k0 += 64) {
        // stage A tile 128x64 (each thread: 4x 16B loads)
        for (int q = 0; q < 4; ++q) {
            int e = (t + 256 * q) * 8;
            int row = e >> 6, col = e & 63;
            *(bf16x8*)&As[row * 72 + col] =
                *(const bf16x8*)(A + (size_t)(m0 + row) * K + k0 + col);
        }
        // stage W tile 64x64
        for (int q = 0; q < 2; ++q) {
            int e = (t + 256 * q) * 8;
            int row = e >> 6, col = e & 63;
            *(bf16x8*)&Ws[row * 72 + col] =
                *(const bf16x8*)(W + (size_t)(n0 + row) * K + k0 + col);
        }
        __syncthreads();
        for (int ks = 0; ks < 2; ++ks) {
            bf16x8 a[4], b[2];
            for (int fm = 0; fm < 4; ++fm)
                a[fm] = *(const bf16x8*)&As[(wr * 64 + fm * 16 + ln) * 72 + ks * 32 + 8 * g];
            for (int fn = 0; fn < 2; ++fn)
                b[fn] = *(const bf16x8*)&Ws[(wc * 32 + fn * 16 + ln) * 72 + ks * 32 + 8 * g];
            for (int fm = 0; fm < 4; ++fm)
                for (int fn = 0; fn < 2; ++fn)
                    acc[fm][fn] = __builtin_amdgcn_mfma_f32_16x16x32_bf16(
                        a[fm], b[fn], acc[fm][fn], 0, 0, 0);
        }
        __syncthreads();
    }

    // epilogue: C/D layout col=lane&15, row=4*(lane>>4)+reg  [measured m89/m91]
    for (int fm = 0; fm < 4; ++fm)
        for (int fn = 0; fn < 2; ++fn)
            for (int r = 0; r < 4; ++r) {
                int row = m0 + wr * 64 + fm * 16 + 4 * g + r;
                int col = n0 + wc * 32 + fn * 16 + ln;
                float val = acc[fm][fn][r];
                if (bias) val += bias[col];
                size_t o = obase + (size_t)row * N + col;
                if (outF) outF[o] = val;
                if (outB) outB[o] = f2b(val);
            }
}

// Flash attention: grid (T/64, H, B), 256 threads = 4 waves.
// Wave w owns q rows [qt*64 + 16w, +16). K = latent[b] (T x 64), V = v[b,:,h*64..] (T x 64).
__global__ __launch_bounds__(256) void attn_kernel(
    const ushort* __restrict__ lt, const ushort* __restrict__ latent,
    const ushort* __restrict__ v, ushort* __restrict__ y)
{
    __shared__ ushort Qs[64 * 72];
    __shared__ ushort Ks[64 * 72];
    __shared__ ushort Vt[64 * 72];      // V transposed: Vt[d][key]
    __shared__ ushort Ps[4][16 * 72];   // per-wave P scratch

    const int T = 2048, C = 1024;
    int qt = blockIdx.x, h = blockIdx.y, b = blockIdx.z;
    int t = threadIdx.x, wave = t >> 6, lane = t & 63;
    int g = lane >> 4, ln = lane & 15;

    const ushort* Qg = lt + ((size_t)(b * N_HEAD + h) * T + qt * 64) * RANK;
    const ushort* Kg = latent + (size_t)b * T * RANK;
    const ushort* Vg = v + (size_t)b * T * C + h * 64;

    // load Q tile once
    for (int q = 0; q < 2; ++q) {
        int e = (t + 256 * q) * 8;
        int row = e >> 6, col = e & 63;
        *(bf16x8*)&Qs[row * 72 + col] = *(const bf16x8*)(Qg + row * RANK + col);
    }
    __syncthreads();
    bf16x8 qa[2];
    qa[0] = *(const bf16x8*)&Qs[(wave * 16 + ln) * 72 + 0 + 8 * g];
    qa[1] = *(const bf16x8*)&Qs[(wave * 16 + ln) * 72 + 32 + 8 * g];

    float m[4], l[4];
    f32x4 o[4];
    for (int r = 0; r < 4; ++r) { m[r] = -INFINITY; l[r] = 0.f; }
    for (int fn = 0; fn < 4; ++fn) o[fn] = (f32x4){0.f, 0.f, 0.f, 0.f};
    const float scale = 0.125f;  // 1/sqrt(64)

    for (int kt = 0; kt <= qt; ++kt) {
        __syncthreads();  // protect K/V LDS from previous iteration's readers
        for (int q = 0; q < 2; ++q) {
            int e = (t + 256 * q) * 8;
            int row = e >> 6, col = e & 63;
            *(bf16x8*)&Ks[row * 72 + col] =
                *(const bf16x8*)(Kg + (size_t)(kt * 64 + row) * RANK + col);
            bf16x8 vv = *(const bf16x8*)(Vg + (size_t)(kt * 64 + row) * C + col);
            for (int j = 0; j < 8; ++j)
                Vt[(col + j) * 72 + row] = ((ushort*)&vv)[j];
        }
        __syncthreads();

        // S = Q @ K^T (16x64 per wave)
        f32x4 s[4];
        for (int fn = 0; fn < 4; ++fn) s[fn] = (f32x4){0.f, 0.f, 0.f, 0.f};
        for (int ks = 0; ks < 2; ++ks)
            for (int fn = 0; fn < 4; ++fn) {
                bf16x8 kb = *(const bf16x8*)&Ks[(fn * 16 + ln) * 72 + ks * 32 + 8 * g];
                s[fn] = __builtin_amdgcn_mfma_f32_16x16x32_bf16(qa[ks], kb, s[fn], 0, 0, 0);
            }

        // scale + causal mask + row max
        int qrow_base = qt * 64 + wave * 16 + 4 * g;
        float rm[4];
        for (int r = 0; r < 4; ++r) rm[r] = -INFINITY;
        for (int fn = 0; fn < 4; ++fn) {
            int key = kt * 64 + fn * 16 + ln;
            for (int r = 0; r < 4; ++r) {
                float sv = s[fn][r] * scale;
                if (key > qrow_base + r) sv = -INFINITY;
                s[fn][r] = sv;
                rm[r] = fmaxf(rm[r], sv);
            }
        }
        for (int off = 1; off < 16; off <<= 1)
            for (int r = 0; r < 4; ++r) rm[r] = fmaxf(rm[r], __shfl_xor(rm[r], off));

        // online softmax update
        float alpha[4], rs[4];
        for (int r = 0; r < 4; ++r) {
            float mn = fmaxf(m[r], rm[r]);
            alpha[r] = expf(m[r] - mn);
            m[r] = mn;
            rs[r] = 0.f;
        }
        for (int fn = 0; fn < 4; ++fn)
            for (int r = 0; r < 4; ++r) {
                float p = expf(s[fn][r] - m[r]);  // masked -> exp(-inf)=0
                s[fn][r] = p;
                rs[r] += p;
            }
        for (int off = 1; off < 16; off <<= 1)
            for (int r = 0; r < 4; ++r) rs[r] += __shfl_xor(rs[r], off);
        for (int r = 0; r < 4; ++r) l[r] = l[r] * alpha[r] + rs[r];
        for (int fn = 0; fn < 4; ++fn)
            for (int r = 0; r < 4; ++r) o[fn][r] *= alpha[r];

        // P -> LDS (bf16, per-wave buffer), then O += P @ V
        ushort* Pw = Ps[wave];
        for (int fn = 0; fn < 4; ++fn)
            for (int r = 0; r < 4; ++r)
                Pw[(4 * g + r) * 72 + fn * 16 + ln] = f2b(s[fn][r]);
        __syncthreads();  // conservative: also orders P write vs read across scheduler
        for (int ks = 0; ks < 2; ++ks) {
            bf16x8 pa = *(const bf16x8*)&Pw[ln * 72 + ks * 32 + 8 * g];
            for (int fn = 0; fn < 4; ++fn) {
                bf16x8 vb = *(const bf16x8*)&Vt[(fn * 16 + ln) * 72 + ks * 32 + 8 * g];
                o[fn] = __builtin_amdgcn_mfma_f32_16x16x32_bf16(pa, vb, o[fn], 0, 0, 0);
            }
        }
    }

    // write y (bf16) in [B,T,C] layout, col = h*64 + d
    for (int fn = 0; fn < 4; ++fn)
        for (int r = 0; r < 4; ++r) {
            int row = qt * 64 + wave * 16 + 4 * g + r;
            y[((size_t)b * T + row) * C + h * 64 + fn * 16 + ln] = f2b(o[fn][r] / l[r]);
        }
}

extern "C" void kernel_launch(void* const* d_in, const int* in_sizes, int n_in,
                              void* d_out, int out_size, void* d_ws, size_t ws_size,
                              hipStream_t stream) {
    const float* hs    = (const float*)d_in[0];
    const float* basis = (const float*)d_in[1];
    const float* core  = (const float*)d_in[2];
    const float* resid = (const float*)d_in[3];
    const float* v_w   = (const float*)d_in[4];
    const float* v_b   = (const float*)d_in[5];
    const float* o_w   = (const float*)d_in[6];
    const float* o_b   = (const float*)d_in[7];
    float* out = (float*)d_out;

    const int B = 4, T = 2048, C = 1024, H = N_HEAD, R = RANK;
    const int M = B * T;  // 8192

    char* ws = (char*)d_ws;
    ushort* hs_b    = (ushort*)(ws + 0);         // 16,777,216 B
    ushort* y_b     = hs_b;                      // alias: hs last read by v-gemm, y written later
    ushort* basis_b = (ushort*)(ws + 16777216);  // 131,072
    ushort* vw_b    = (ushort*)(ws + 16908288);  // 2,097,152
    ushort* ow_b    = (ushort*)(ws + 19005440);  // 2,097,152
    ushort* hm_b    = (ushort*)(ws + 21102592);  // 131,072
    ushort* lat_b   = (ushort*)(ws + 21233664);  // 1,048,576
    ushort* lt_b    = (ushort*)(ws + 22282240);  // 16,777,216
    ushort* v_bf    = (ushort*)(ws + 39059456);  // 16,777,216
    // total 55,836,672 bytes

    // 1. convert inputs to bf16
    cvt_kernel<<<dim3(M * C / 4 / 256), 256, 0, stream>>>(hs, hs_b, M * C / 4);
    cvt_kernel<<<dim3(R * C / 4 / 256), 256, 0, stream>>>(basis, basis_b, R * C / 4);
    cvt_kernel<<<dim3(C * C / 4 / 256), 256, 0, stream>>>(v_w, vw_b, C * C / 4);
    cvt_kernel<<<dim3(C * C / 4 / 256), 256, 0, stream>>>(o_w, ow_b, C * C / 4);

    // 2. head matrices (transposed, bf16)
    headmats_kernel<<<dim3(16), 256, 0, stream>>>(core, resid, hm_b);

    // 3. latent = hs @ basis^T : [8192,64]
    gemm_nt<<<dim3(1, M / 128, 1), 256, 0, stream>>>(
        hs_b, basis_b, nullptr, nullptr, lat_b, M, R, C, 1, 0, 1, 0, 0);

    // 4. v = hs @ v_w^T + v_b : [8192,1024]
    gemm_nt<<<dim3(C / 64, M / 128, 1), 256, 0, stream>>>(
        hs_b, vw_b, v_b, nullptr, v_bf, M, C, C, 1, 0, 1, 0, 0);

    // 5. lt[b,h] = latent[b] @ hmT[h]^T : batched z = b*H+h, [2048,64] each
    gemm_nt<<<dim3(1, T / 128, B * H), 256, 0, stream>>>(
        lat_b, hm_b, nullptr, nullptr, lt_b, T, R, R,
        H, (long long)T * R, H, (long long)R * R, (long long)T * R);

    // 6. flash attention -> y bf16 [B,T,C]
    attn_kernel<<<dim3(T / 64, H, B), 256, 0, stream>>>(lt_b, lat_b, v_bf, y_b);

    // 7. out = y @ o_w^T + o_b : f32
    gemm_nt<<<dim3(C / 64, M / 128, 1), 256, 0, stream>>>(
        y_b, ow_b, o_b, out, nullptr, M, C, C, 1, 0, 1, 0, 0);
}

// Round 6
// 436.920 us; speedup vs baseline: 1.2543x; 1.2543x over previous
//
#include <hip/hip_runtime.h>
#include <hip/hip_bf16.h>

// GPT2 symmetric latent attention, MI355X (gfx950)
// B=4 T=2048 C=1024 H=16 R=64 head_dim=64
//
// Pipeline:
//  1. cvt f32->bf16: hs, basis_w, v_w, o_w
//  2. head_mats: hmT[h][s][r] = core_sym[r][s]/H + centered resid (bf16)
//  3. latent = hs @ basis^T            (MFMA NT gemm, 8192x64, K=1024)
//  4. vT     = (hs @ v_w^T + v_b)^T    (written as [B,H,64,T] bf16)
//  5. lt     = latent @ hmT^T batched  (per (b,h): 2048x64, K=64)
//  6. flash attention (128 q/block, 4 waves x 32 q-rows, KV tile 64,
//     XOR-swizzled LDS, log2-domain online softmax, defer-max) -> y bf16
//  7. out    = y @ o_w^T + o_b (f32)

#define N_HEAD 16
#define RANK 64

typedef __attribute__((ext_vector_type(8))) short bf16x8;
typedef __attribute__((ext_vector_type(4))) float f32x4;

__device__ __forceinline__ ushort f2b(float f) {
    // round-to-nearest-even f32 -> bf16
    unsigned u = __builtin_bit_cast(unsigned, f);
    u += 0x7fffu + ((u >> 16) & 1u);
    return (ushort)(u >> 16);
}

// LDS swizzle: element (row,col) of a [R][64]-ushort tile stored at col ^ ((row&7)<<3).
// 128B row stride; spreads column-slice reads across all 8 16B chunk slots (G4 recipe).
__device__ __forceinline__ int swz(int row, int col) {
    return (row << 6) | (col ^ ((row & 7) << 3));
}

__global__ void cvt_kernel(const float* __restrict__ src, ushort* __restrict__ dst, int n4) {
    int i = blockIdx.x * blockDim.x + threadIdx.x;
    if (i >= n4) return;
    float4 v = ((const float4*)src)[i];
    ushort4 o;
    o.x = f2b(v.x); o.y = f2b(v.y); o.z = f2b(v.z); o.w = f2b(v.w);
    ((ushort4*)dst)[i] = o;
}

// head_mats^T in bf16: hmT[h][s][r] = core_sym[r][s]/H + (resid[h][r][s] - mean_h resid[.][r][s])
__global__ void headmats_kernel(const float* __restrict__ core,
                                const float* __restrict__ resid,
                                ushort* __restrict__ hmT) {
    int idx = blockIdx.x * 256 + threadIdx.x;  // (r,s) flat, 4096 total
    if (idx >= RANK * RANK) return;
    int r = idx >> 6, s = idx & 63;
    float mean = 0.f;
    for (int h = 0; h < N_HEAD; ++h) mean += resid[h * RANK * RANK + idx];
    mean *= (1.0f / N_HEAD);
    float cs = 0.5f * (core[r * RANK + s] + core[s * RANK + r]) * (1.0f / N_HEAD);
    for (int h = 0; h < N_HEAD; ++h) {
        float val = cs + resid[h * RANK * RANK + idx] - mean;
        hmT[h * RANK * RANK + s * RANK + r] = f2b(val);
    }
}

// Generic NT GEMM: C[m,n] = sum_k A[m,k] * W[n,k] (+bias[n]).
// A,W bf16 row-major; out f32 and/or bf16. 128x64 tile, BK=64, 4 waves (2x2).
// Batched via blockIdx.z. outVT=1: write bf16 transposed as vT[b*1024+col][t] (T=2048).
__global__ __launch_bounds__(256) void gemm_nt(
    const ushort* __restrict__ A, const ushort* __restrict__ W,
    const float* __restrict__ bias,
    float* __restrict__ outF, ushort* __restrict__ outB,
    int M, int N, int K,
    int zDivA, long long aStride, int zModW, long long wStride, long long oStride,
    int outVT)
{
    __shared__ ushort As[128 * 72];  // +8 pad: 2-way bank alias (free)
    __shared__ ushort Ws[64 * 72];

    int z = blockIdx.z;
    A += (size_t)(z / zDivA) * aStride;
    W += (size_t)(z % zModW) * wStride;
    size_t obase = (size_t)z * oStride;

    int m0 = blockIdx.y * 128;
    int n0 = blockIdx.x * 64;
    int t = threadIdx.x;
    int wave = t >> 6, lane = t & 63;
    int wr = wave >> 1, wc = wave & 1;
    int g = lane >> 4, ln = lane & 15;

    f32x4 acc[4][2];
    for (int i = 0; i < 4; ++i)
        for (int j = 0; j < 2; ++j) acc[i][j] = (f32x4){0.f, 0.f, 0.f, 0.f};

    for (int k0 = 0; k0 < K; k0 += 64) {
        for (int q = 0; q < 4; ++q) {
            int e = (t + 256 * q) * 8;
            int row = e >> 6, col = e & 63;
            *(bf16x8*)&As[row * 72 + col] =
                *(const bf16x8*)(A + (size_t)(m0 + row) * K + k0 + col);
        }
        for (int q = 0; q < 2; ++q) {
            int e = (t + 256 * q) * 8;
            int row = e >> 6, col = e & 63;
            *(bf16x8*)&Ws[row * 72 + col] =
                *(const bf16x8*)(W + (size_t)(n0 + row) * K + k0 + col);
        }
        __syncthreads();
        for (int ks = 0; ks < 2; ++ks) {
            bf16x8 a[4], b[2];
            for (int fm = 0; fm < 4; ++fm)
                a[fm] = *(const bf16x8*)&As[(wr * 64 + fm * 16 + ln) * 72 + ks * 32 + 8 * g];
            for (int fn = 0; fn < 2; ++fn)
                b[fn] = *(const bf16x8*)&Ws[(wc * 32 + fn * 16 + ln) * 72 + ks * 32 + 8 * g];
            for (int fm = 0; fm < 4; ++fm)
                for (int fn = 0; fn < 2; ++fn)
                    acc[fm][fn] = __builtin_amdgcn_mfma_f32_16x16x32_bf16(
                        a[fm], b[fn], acc[fm][fn], 0, 0, 0);
        }
        __syncthreads();
    }

    // C/D layout: col=lane&15, row=4*(lane>>4)+reg  [measured m89/m91]
    if (outVT) {
        for (int fm = 0; fm < 4; ++fm)
            for (int fn = 0; fn < 2; ++fn) {
                int row = m0 + wr * 64 + fm * 16 + 4 * g;   // + r, 4 consecutive t's
                int col = n0 + wc * 32 + fn * 16 + ln;
                float bv = bias ? bias[col] : 0.f;
                ushort4 us;
                us.x = f2b(acc[fm][fn][0] + bv);
                us.y = f2b(acc[fm][fn][1] + bv);
                us.z = f2b(acc[fm][fn][2] + bv);
                us.w = f2b(acc[fm][fn][3] + bv);
                size_t off = ((size_t)(row >> 11) * 1024 + col) * 2048 + (row & 2047);
                *(ushort4*)(outB + off) = us;
            }
    } else {
        for (int fm = 0; fm < 4; ++fm)
            for (int fn = 0; fn < 2; ++fn)
                for (int r = 0; r < 4; ++r) {
                    int row = m0 + wr * 64 + fm * 16 + 4 * g + r;
                    int col = n0 + wc * 32 + fn * 16 + ln;
                    float val = acc[fm][fn][r];
                    if (bias) val += bias[col];
                    size_t o = obase + (size_t)row * N + col;
                    if (outF) outF[o] = val;
                    if (outB) outB[o] = f2b(val);
                }
    }
}

// Flash attention: grid (T/128, H, B), 256 threads = 4 waves.
// Wave w owns q rows [qt*128 + 32w, +32). K = latent[b] (Tx64), V^T = vT[b,h] (64xT).
__global__ __launch_bounds__(256) void attn_kernel(
    const ushort* __restrict__ lt, const ushort* __restrict__ latent,
    const ushort* __restrict__ vT, ushort* __restrict__ y)
{
    const int T = 2048, C = 1024;
    __shared__ ushort Ks[64 * 64];      // swizzled, row = key
    __shared__ ushort Vs[64 * 64];      // swizzled, row = d, col = key
    __shared__ ushort Ps[4][32 * 64];   // per-wave P, row = local q, col = key

    int qt = blockIdx.x, h = blockIdx.y, b = blockIdx.z;
    int t = threadIdx.x, w = t >> 6, lane = t & 63;
    int g = lane >> 4, ln = lane & 15;

    const ushort* Qg = lt + ((size_t)(b * N_HEAD + h) * T + qt * 128 + w * 32) * RANK;
    const ushort* Kg = latent + (size_t)b * T * RANK;
    const ushort* Vg = vT + (size_t)(b * N_HEAD + h) * 64 * T;

    // Q fragments straight from global (once)
    bf16x8 qa[2][2];
    for (int m = 0; m < 2; ++m)
        for (int ks = 0; ks < 2; ++ks)
            qa[m][ks] = *(const bf16x8*)(Qg + (size_t)(m * 16 + ln) * RANK + ks * 32 + 8 * g);

    float mr[2][4], lr[2][4];
    f32x4 o[2][4];
    for (int m = 0; m < 2; ++m)
        for (int r = 0; r < 4; ++r) { mr[m][r] = -INFINITY; lr[m][r] = 0.f; }
    for (int m = 0; m < 2; ++m)
        for (int fn = 0; fn < 4; ++fn) o[m][fn] = (f32x4){0.f, 0.f, 0.f, 0.f};

    const float SCL = 0.125f * 1.44269504089f;  // 1/sqrt(R) folded into log2 domain
    const float THR = 11.5f;                    // defer-max threshold (~8 nats)

    int srow = t >> 3, scol = (t & 7) * 8;      // staging: 8 threads/row, 16B each
    ushort* Pw = Ps[w];

    int kmax = 2 * qt + 1;
    for (int kt = 0; kt <= kmax; ++kt) {
        __syncthreads();  // previous iteration's K/V readers done
        for (int q = 0; q < 2; ++q) {
            int row = srow + q * 32;
            *(bf16x8*)&Ks[swz(row, scol)] =
                *(const bf16x8*)(Kg + (size_t)(kt * 64 + row) * RANK + scol);
            *(bf16x8*)&Vs[swz(row, scol)] =
                *(const bf16x8*)(Vg + (size_t)row * T + kt * 64 + scol);
        }
        __syncthreads();

        // S = Q @ K^T (32 x 64 per wave)
        f32x4 s[2][4];
        for (int m = 0; m < 2; ++m)
            for (int fn = 0; fn < 4; ++fn) s[m][fn] = (f32x4){0.f, 0.f, 0.f, 0.f};
        for (int ks = 0; ks < 2; ++ks) {
            bf16x8 kb[4];
            for (int fn = 0; fn < 4; ++fn)
                kb[fn] = *(const bf16x8*)&Ks[swz(fn * 16 + ln, ks * 32 + 8 * g)];
            for (int m = 0; m < 2; ++m)
                for (int fn = 0; fn < 4; ++fn)
                    s[m][fn] = __builtin_amdgcn_mfma_f32_16x16x32_bf16(
                        qa[m][ks], kb[fn], s[m][fn], 0, 0, 0);
        }

        // scale (log2 domain) + causal mask (skipped for full tiles) + row max
        float rm[2][4];
        for (int m = 0; m < 2; ++m)
            for (int r = 0; r < 4; ++r) rm[m][r] = -INFINITY;
        for (int m = 0; m < 2; ++m) {
            int qb = qt * 128 + w * 32 + m * 16 + 4 * g;
            bool needmask = (kt * 64 + 63) > (qt * 128 + w * 32 + m * 16);
            for (int fn = 0; fn < 4; ++fn) {
                int key = kt * 64 + fn * 16 + ln;
                for (int r = 0; r < 4; ++r) {
                    float sv = s[m][fn][r] * SCL;
                    if (needmask && key > qb + r) sv = -INFINITY;
                    s[m][fn][r] = sv;
                    rm[m][r] = fmaxf(rm[m][r], sv);
                }
            }
        }
        for (int off = 1; off < 16; off <<= 1)
            for (int m = 0; m < 2; ++m)
                for (int r = 0; r < 4; ++r)
                    rm[m][r] = fmaxf(rm[m][r], __shfl_xor(rm[m][r], off));

        // defer-max: rescale only when max grew by > THR
        bool need = false;
        for (int m = 0; m < 2; ++m)
            for (int r = 0; r < 4; ++r) need |= rm[m][r] > mr[m][r] + THR;
        if (__any((int)need)) {
            for (int m = 0; m < 2; ++m)
                for (int r = 0; r < 4; ++r) {
                    float nm = fmaxf(mr[m][r], rm[m][r]);
                    float al = exp2f(mr[m][r] - nm);
                    mr[m][r] = nm;
                    lr[m][r] *= al;
                    for (int fn = 0; fn < 4; ++fn) o[m][fn][r] *= al;
                }
        }

        // P = exp2(s - m), row sums
        float rs[2][4];
        for (int m = 0; m < 2; ++m)
            for (int r = 0; r < 4; ++r) rs[m][r] = 0.f;
        for (int m = 0; m < 2; ++m)
            for (int fn = 0; fn < 4; ++fn)
                for (int r = 0; r < 4; ++r) {
                    float p = exp2f(s[m][fn][r] - mr[m][r]);
                    s[m][fn][r] = p;
                    rs[m][r] += p;
                }
        for (int off = 1; off < 16; off <<= 1)
            for (int m = 0; m < 2; ++m)
                for (int r = 0; r < 4; ++r) rs[m][r] += __shfl_xor(rs[m][r], off);
        for (int m = 0; m < 2; ++m)
            for (int r = 0; r < 4; ++r) lr[m][r] += rs[m][r];

        // P -> wave-private LDS (bf16, swizzled); same-wave dep ordered by lgkmcnt
        for (int m = 0; m < 2; ++m)
            for (int fn = 0; fn < 4; ++fn)
                for (int r = 0; r < 4; ++r)
                    Pw[swz(m * 16 + 4 * g + r, fn * 16 + ln)] = f2b(s[m][fn][r]);

        // O += P @ V
        for (int ks = 0; ks < 2; ++ks) {
            bf16x8 vb[4];
            for (int fn = 0; fn < 4; ++fn)
                vb[fn] = *(const bf16x8*)&Vs[swz(fn * 16 + ln, ks * 32 + 8 * g)];
            for (int m = 0; m < 2; ++m) {
                bf16x8 pa = *(const bf16x8*)&Pw[swz(m * 16 + ln, ks * 32 + 8 * g)];
                for (int fn = 0; fn < 4; ++fn)
                    o[m][fn] = __builtin_amdgcn_mfma_f32_16x16x32_bf16(
                        pa, vb[fn], o[m][fn], 0, 0, 0);
            }
        }
    }

    // write y (bf16) in [B,T,C], col = h*64 + d
    for (int m = 0; m < 2; ++m)
        for (int fn = 0; fn < 4; ++fn)
            for (int r = 0; r < 4; ++r) {
                int row = qt * 128 + w * 32 + m * 16 + 4 * g + r;
                y[((size_t)b * T + row) * C + h * 64 + fn * 16 + ln] =
                    f2b(o[m][fn][r] / lr[m][r]);
            }
}

extern "C" void kernel_launch(void* const* d_in, const int* in_sizes, int n_in,
                              void* d_out, int out_size, void* d_ws, size_t ws_size,
                              hipStream_t stream) {
    const float* hs    = (const float*)d_in[0];
    const float* basis = (const float*)d_in[1];
    const float* core  = (const float*)d_in[2];
    const float* resid = (const float*)d_in[3];
    const float* v_w   = (const float*)d_in[4];
    const float* v_b   = (const float*)d_in[5];
    const float* o_w   = (const float*)d_in[6];
    const float* o_b   = (const float*)d_in[7];
    float* out = (float*)d_out;

    const int B = 4, T = 2048, C = 1024, H = N_HEAD, R = RANK;
    const int M = B * T;  // 8192

    char* ws = (char*)d_ws;
    ushort* hs_b    = (ushort*)(ws + 0);         // 16,777,216 B
    ushort* y_b     = hs_b;                      // alias: hs dead after v-gemm
    ushort* basis_b = (ushort*)(ws + 16777216);  // 131,072
    ushort* vw_b    = (ushort*)(ws + 16908288);  // 2,097,152
    ushort* ow_b    = (ushort*)(ws + 19005440);  // 2,097,152
    ushort* hm_b    = (ushort*)(ws + 21102592);  // 131,072
    ushort* lat_b   = (ushort*)(ws + 21233664);  // 1,048,576
    ushort* lt_b    = (ushort*)(ws + 22282240);  // 16,777,216
    ushort* vT_b    = (ushort*)(ws + 39059456);  // 16,777,216  [B,H,64,T]

    // 1. convert inputs to bf16
    cvt_kernel<<<dim3(M * C / 4 / 256), 256, 0, stream>>>(hs, hs_b, M * C / 4);
    cvt_kernel<<<dim3(R * C / 4 / 256), 256, 0, stream>>>(basis, basis_b, R * C / 4);
    cvt_kernel<<<dim3(C * C / 4 / 256), 256, 0, stream>>>(v_w, vw_b, C * C / 4);
    cvt_kernel<<<dim3(C * C / 4 / 256), 256, 0, stream>>>(o_w, ow_b, C * C / 4);

    // 2. head matrices (transposed, bf16)
    headmats_kernel<<<dim3(16), 256, 0, stream>>>(core, resid, hm_b);

    // 3. latent = hs @ basis^T : [8192,64]
    gemm_nt<<<dim3(1, M / 128, 1), 256, 0, stream>>>(
        hs_b, basis_b, nullptr, nullptr, lat_b, M, R, C, 1, 0, 1, 0, 0, 0);

    // 4. vT = (hs @ v_w^T + v_b)^T : [B,H,64,T] bf16
    gemm_nt<<<dim3(C / 64, M / 128, 1), 256, 0, stream>>>(
        hs_b, vw_b, v_b, nullptr, vT_b, M, C, C, 1, 0, 1, 0, 0, 1);

    // 5. lt[b,h] = latent[b] @ hmT[h]^T : batched z = b*H+h
    gemm_nt<<<dim3(1, T / 128, B * H), 256, 0, stream>>>(
        lat_b, hm_b, nullptr, nullptr, lt_b, T, R, R,
        H, (long long)T * R, H, (long long)R * R, (long long)T * R, 0);

    // 6. flash attention -> y bf16 [B,T,C]
    attn_kernel<<<dim3(T / 128, H, B), 256, 0, stream>>>(lt_b, lat_b, vT_b, y_b);

    // 7. out = y @ o_w^T + o_b : f32
    gemm_nt<<<dim3(C / 64, M / 128, 1), 256, 0, stream>>>(
        y_b, ow_b, o_b, out, nullptr, M, C, C, 1, 0, 1, 0, 0, 0);
}

// Round 7
// 340.507 us; speedup vs baseline: 1.6095x; 1.2831x over previous
//
#include <hip/hip_runtime.h>
#include <hip/hip_bf16.h>

// GPT2 symmetric latent attention, MI355X (gfx950)
// B=4 T=2048 C=1024 H=16 R=64 head_dim=64
//
// Pipeline:
//  1. cvt f32->bf16: hs, basis_w, v_w, o_w
//  2. head_mats: hmT[h][s][r] = core_sym[r][s]/H + centered resid (bf16)
//  3. latent = hs @ basis^T            (MFMA NT gemm, 8192x64, K=1024)
//  4. vT     = (hs @ v_w^T + v_b)^T    (written as [B,H,64,T] bf16)
//  5. lt     = latent @ hmT^T batched  (per (b,h): 2048x64, K=64)
//  6. flash attention v2: barrier-free (K/V frags straight from L2),
//     paired q-tiles for load balance, reduction-free common-path softmax
//  7. out    = y @ o_w^T + o_b (f32)

#define N_HEAD 16
#define RANK 64

typedef __attribute__((ext_vector_type(8))) short bf16x8;
typedef __attribute__((ext_vector_type(4))) float f32x4;

__device__ __forceinline__ ushort f2b(float f) {
    // round-to-nearest-even f32 -> bf16
    unsigned u = __builtin_bit_cast(unsigned, f);
    u += 0x7fffu + ((u >> 16) & 1u);
    return (ushort)(u >> 16);
}

// LDS swizzle for [32][64]-ushort P tile: col ^ ((row&7)<<3); conflict-free column reads.
__device__ __forceinline__ int swz(int row, int col) {
    return (row << 6) | (col ^ ((row & 7) << 3));
}

__global__ void cvt_kernel(const float* __restrict__ src, ushort* __restrict__ dst, int n4) {
    int i = blockIdx.x * blockDim.x + threadIdx.x;
    if (i >= n4) return;
    float4 v = ((const float4*)src)[i];
    ushort4 o;
    o.x = f2b(v.x); o.y = f2b(v.y); o.z = f2b(v.z); o.w = f2b(v.w);
    ((ushort4*)dst)[i] = o;
}

// head_mats^T in bf16: hmT[h][s][r] = core_sym[r][s]/H + (resid[h][r][s] - mean_h resid[.][r][s])
__global__ void headmats_kernel(const float* __restrict__ core,
                                const float* __restrict__ resid,
                                ushort* __restrict__ hmT) {
    int idx = blockIdx.x * 256 + threadIdx.x;
    if (idx >= RANK * RANK) return;
    int r = idx >> 6, s = idx & 63;
    float mean = 0.f;
    for (int h = 0; h < N_HEAD; ++h) mean += resid[h * RANK * RANK + idx];
    mean *= (1.0f / N_HEAD);
    float cs = 0.5f * (core[r * RANK + s] + core[s * RANK + r]) * (1.0f / N_HEAD);
    for (int h = 0; h < N_HEAD; ++h) {
        float val = cs + resid[h * RANK * RANK + idx] - mean;
        hmT[h * RANK * RANK + s * RANK + r] = f2b(val);
    }
}

// Generic NT GEMM (unchanged from R1): 128x64 tile, BK=64, 4 waves.
__global__ __launch_bounds__(256) void gemm_nt(
    const ushort* __restrict__ A, const ushort* __restrict__ W,
    const float* __restrict__ bias,
    float* __restrict__ outF, ushort* __restrict__ outB,
    int M, int N, int K,
    int zDivA, long long aStride, int zModW, long long wStride, long long oStride,
    int outVT)
{
    __shared__ ushort As[128 * 72];
    __shared__ ushort Ws[64 * 72];

    int z = blockIdx.z;
    A += (size_t)(z / zDivA) * aStride;
    W += (size_t)(z % zModW) * wStride;
    size_t obase = (size_t)z * oStride;

    int m0 = blockIdx.y * 128;
    int n0 = blockIdx.x * 64;
    int t = threadIdx.x;
    int wave = t >> 6, lane = t & 63;
    int wr = wave >> 1, wc = wave & 1;
    int g = lane >> 4, ln = lane & 15;

    f32x4 acc[4][2];
    for (int i = 0; i < 4; ++i)
        for (int j = 0; j < 2; ++j) acc[i][j] = (f32x4){0.f, 0.f, 0.f, 0.f};

    for (int k0 = 0; k0 < K; k0 += 64) {
        for (int q = 0; q < 4; ++q) {
            int e = (t + 256 * q) * 8;
            int row = e >> 6, col = e & 63;
            *(bf16x8*)&As[row * 72 + col] =
                *(const bf16x8*)(A + (size_t)(m0 + row) * K + k0 + col);
        }
        for (int q = 0; q < 2; ++q) {
            int e = (t + 256 * q) * 8;
            int row = e >> 6, col = e & 63;
            *(bf16x8*)&Ws[row * 72 + col] =
                *(const bf16x8*)(W + (size_t)(n0 + row) * K + k0 + col);
        }
        __syncthreads();
        for (int ks = 0; ks < 2; ++ks) {
            bf16x8 a[4], b[2];
            for (int fm = 0; fm < 4; ++fm)
                a[fm] = *(const bf16x8*)&As[(wr * 64 + fm * 16 + ln) * 72 + ks * 32 + 8 * g];
            for (int fn = 0; fn < 2; ++fn)
                b[fn] = *(const bf16x8*)&Ws[(wc * 32 + fn * 16 + ln) * 72 + ks * 32 + 8 * g];
            for (int fm = 0; fm < 4; ++fm)
                for (int fn = 0; fn < 2; ++fn)
                    acc[fm][fn] = __builtin_amdgcn_mfma_f32_16x16x32_bf16(
                        a[fm], b[fn], acc[fm][fn], 0, 0, 0);
        }
        __syncthreads();
    }

    if (outVT) {
        for (int fm = 0; fm < 4; ++fm)
            for (int fn = 0; fn < 2; ++fn) {
                int row = m0 + wr * 64 + fm * 16 + 4 * g;
                int col = n0 + wc * 32 + fn * 16 + ln;
                float bv = bias ? bias[col] : 0.f;
                ushort4 us;
                us.x = f2b(acc[fm][fn][0] + bv);
                us.y = f2b(acc[fm][fn][1] + bv);
                us.z = f2b(acc[fm][fn][2] + bv);
                us.w = f2b(acc[fm][fn][3] + bv);
                size_t off = ((size_t)(row >> 11) * 1024 + col) * 2048 + (row & 2047);
                *(ushort4*)(outB + off) = us;
            }
    } else {
        for (int fm = 0; fm < 4; ++fm)
            for (int fn = 0; fn < 2; ++fn)
                for (int r = 0; r < 4; ++r) {
                    int row = m0 + wr * 64 + fm * 16 + 4 * g + r;
                    int col = n0 + wc * 32 + fn * 16 + ln;
                    float val = acc[fm][fn][r];
                    if (bias) val += bias[col];
                    size_t o = obase + (size_t)row * N + col;
                    if (outF) outF[o] = val;
                    if (outB) outB[o] = f2b(val);
                }
    }
}

// Flash attention v2: grid (8, H, B), 256 thr = 4 waves, NO barriers.
// Block processes q-tiles {pq, 15-pq} sequentially (34 k-tiles total, perfectly balanced).
// Wave w owns 32 q-rows of the current tile. K/V fragments loaded straight from global (L2-hot).
// Softmax: defer-max via __any on UNREDUCED per-lane maxima (no shuffles common path);
// row-sums kept as per-lane partials, reduced once per pass.
__global__ __launch_bounds__(256) void attn_kernel(
    const ushort* __restrict__ lt, const ushort* __restrict__ latent,
    const ushort* __restrict__ vT, ushort* __restrict__ y)
{
    const int T = 2048, C = 1024;
    __shared__ ushort Ps[4][32 * 64];   // per-wave P, swizzled

    int pq = blockIdx.x, h = blockIdx.y, b = blockIdx.z;
    int t = threadIdx.x, w = t >> 6, lane = t & 63;
    int g = lane >> 4, ln = lane & 15;

    const ushort* Kg = latent + (size_t)b * T * RANK;
    const ushort* Vg = vT + (size_t)(b * N_HEAD + h) * 64 * T;
    ushort* Pw = Ps[w];

    const float SCL = 0.125f * 1.44269504089f;  // 1/sqrt(R), log2 domain
    const float THR = 11.5f;                    // defer-max threshold (~8 nats)

    for (int pass = 0; pass < 2; ++pass) {
        int qt = pass ? (15 - pq) : pq;
        int qrow0 = qt * 128 + w * 32;

        // Q fragments from global (L2)
        const ushort* Qg = lt + ((size_t)(b * N_HEAD + h) * T + qrow0) * RANK;
        bf16x8 qa[2][2];
        for (int m = 0; m < 2; ++m)
            for (int ks = 0; ks < 2; ++ks)
                qa[m][ks] = *(const bf16x8*)(Qg + (size_t)(m * 16 + ln) * RANK + ks * 32 + 8 * g);

        float mr[2][4], lp[2][4];   // running max (log2), per-lane partial sum
        f32x4 o[2][4];
        for (int m = 0; m < 2; ++m)
            for (int r = 0; r < 4; ++r) { mr[m][r] = -INFINITY; lp[m][r] = 0.f; }
        for (int m = 0; m < 2; ++m)
            for (int fn = 0; fn < 4; ++fn) o[m][fn] = (f32x4){0.f, 0.f, 0.f, 0.f};

        int kmax = 2 * qt + 1;
        for (int kt = 0; kt <= kmax; ++kt) {
            // S = Q @ K^T, K fragments straight from global
            f32x4 s[2][4];
            for (int m = 0; m < 2; ++m)
                for (int fn = 0; fn < 4; ++fn) s[m][fn] = (f32x4){0.f, 0.f, 0.f, 0.f};
            for (int ks = 0; ks < 2; ++ks) {
                bf16x8 kb[4];
                for (int fn = 0; fn < 4; ++fn)
                    kb[fn] = *(const bf16x8*)(Kg +
                        (size_t)(kt * 64 + fn * 16 + ln) * RANK + ks * 32 + 8 * g);
                for (int m = 0; m < 2; ++m)
                    for (int fn = 0; fn < 4; ++fn)
                        s[m][fn] = __builtin_amdgcn_mfma_f32_16x16x32_bf16(
                            qa[m][ks], kb[fn], s[m][fn], 0, 0, 0);
            }

            // V fragments issued early (hide L2 latency under softmax VALU)
            bf16x8 vb[2][4];
            for (int ks = 0; ks < 2; ++ks)
                for (int fn = 0; fn < 4; ++fn)
                    vb[ks][fn] = *(const bf16x8*)(Vg +
                        (size_t)(fn * 16 + ln) * T + kt * 64 + ks * 32 + 8 * g);

            // scale + causal mask + per-lane partial row max (no cross-lane ops)
            float rm[2][4];
            for (int m = 0; m < 2; ++m) {
                for (int r = 0; r < 4; ++r) rm[m][r] = -INFINITY;
                int qb = qrow0 + m * 16 + 4 * g;
                if ((kt * 64 + 63) > (qrow0 + m * 16)) {  // wave-uniform branch
                    for (int fn = 0; fn < 4; ++fn) {
                        int key = kt * 64 + fn * 16 + ln;
                        for (int r = 0; r < 4; ++r) {
                            float sv = s[m][fn][r] * SCL;
                            if (key > qb + r) sv = -INFINITY;
                            s[m][fn][r] = sv;
                            rm[m][r] = fmaxf(rm[m][r], sv);
                        }
                    }
                } else {
                    for (int fn = 0; fn < 4; ++fn)
                        for (int r = 0; r < 4; ++r) {
                            float sv = s[m][fn][r] * SCL;
                            s[m][fn][r] = sv;
                            rm[m][r] = fmaxf(rm[m][r], sv);
                        }
                }
            }

            // defer-max on UNREDUCED maxima: common path has zero shuffles
            int need = 0;
            for (int m = 0; m < 2; ++m)
                for (int r = 0; r < 4; ++r) need |= (rm[m][r] > mr[m][r] + THR);
            if (__any(need)) {
                for (int off = 1; off < 16; off <<= 1)
                    for (int m = 0; m < 2; ++m)
                        for (int r = 0; r < 4; ++r)
                            rm[m][r] = fmaxf(rm[m][r], __shfl_xor(rm[m][r], off));
                for (int m = 0; m < 2; ++m)
                    for (int r = 0; r < 4; ++r) {
                        float nm = fmaxf(mr[m][r], rm[m][r]);
                        float al = exp2f(mr[m][r] - nm);   // uniform across 16-lane group
                        mr[m][r] = nm;
                        lp[m][r] *= al;
                        for (int fn = 0; fn < 4; ++fn) o[m][fn][r] *= al;
                    }
            }

            // P = exp2(s - m); accumulate per-lane partial sums; store P (bf16, swizzled)
            for (int m = 0; m < 2; ++m)
                for (int fn = 0; fn < 4; ++fn)
                    for (int r = 0; r < 4; ++r) {
                        float p = exp2f(s[m][fn][r] - mr[m][r]);
                        lp[m][r] += p;
                        Pw[swz(m * 16 + 4 * g + r, fn * 16 + ln)] = f2b(p);
                    }

            // O += P @ V (P via wave-private LDS; same-wave dep ordered by lgkmcnt)
            for (int ks = 0; ks < 2; ++ks) {
                bf16x8 pa[2];
                for (int m = 0; m < 2; ++m)
                    pa[m] = *(const bf16x8*)&Pw[swz(m * 16 + ln, ks * 32 + 8 * g)];
                for (int m = 0; m < 2; ++m)
                    for (int fn = 0; fn < 4; ++fn)
                        o[m][fn] = __builtin_amdgcn_mfma_f32_16x16x32_bf16(
                            pa[m], vb[ks][fn], o[m][fn], 0, 0, 0);
            }
        }

        // reduce row sums once per pass, then write y
        for (int off = 1; off < 16; off <<= 1)
            for (int m = 0; m < 2; ++m)
                for (int r = 0; r < 4; ++r) lp[m][r] += __shfl_xor(lp[m][r], off);
        for (int m = 0; m < 2; ++m)
            for (int fn = 0; fn < 4; ++fn)
                for (int r = 0; r < 4; ++r) {
                    int row = qrow0 + m * 16 + 4 * g + r;
                    y[((size_t)b * T + row) * C + h * 64 + fn * 16 + ln] =
                        f2b(o[m][fn][r] / lp[m][r]);
                }
    }
}

extern "C" void kernel_launch(void* const* d_in, const int* in_sizes, int n_in,
                              void* d_out, int out_size, void* d_ws, size_t ws_size,
                              hipStream_t stream) {
    const float* hs    = (const float*)d_in[0];
    const float* basis = (const float*)d_in[1];
    const float* core  = (const float*)d_in[2];
    const float* resid = (const float*)d_in[3];
    const float* v_w   = (const float*)d_in[4];
    const float* v_b   = (const float*)d_in[5];
    const float* o_w   = (const float*)d_in[6];
    const float* o_b   = (const float*)d_in[7];
    float* out = (float*)d_out;

    const int B = 4, T = 2048, C = 1024, H = N_HEAD, R = RANK;
    const int M = B * T;  // 8192

    char* ws = (char*)d_ws;
    ushort* hs_b    = (ushort*)(ws + 0);         // 16,777,216 B
    ushort* y_b     = hs_b;                      // alias: hs dead after v-gemm
    ushort* basis_b = (ushort*)(ws + 16777216);  // 131,072
    ushort* vw_b    = (ushort*)(ws + 16908288);  // 2,097,152
    ushort* ow_b    = (ushort*)(ws + 19005440);  // 2,097,152
    ushort* hm_b    = (ushort*)(ws + 21102592);  // 131,072
    ushort* lat_b   = (ushort*)(ws + 21233664);  // 1,048,576
    ushort* lt_b    = (ushort*)(ws + 22282240);  // 16,777,216
    ushort* vT_b    = (ushort*)(ws + 39059456);  // 16,777,216  [B,H,64,T]

    // 1. convert inputs to bf16
    cvt_kernel<<<dim3(M * C / 4 / 256), 256, 0, stream>>>(hs, hs_b, M * C / 4);
    cvt_kernel<<<dim3(R * C / 4 / 256), 256, 0, stream>>>(basis, basis_b, R * C / 4);
    cvt_kernel<<<dim3(C * C / 4 / 256), 256, 0, stream>>>(v_w, vw_b, C * C / 4);
    cvt_kernel<<<dim3(C * C / 4 / 256), 256, 0, stream>>>(o_w, ow_b, C * C / 4);

    // 2. head matrices (transposed, bf16)
    headmats_kernel<<<dim3(16), 256, 0, stream>>>(core, resid, hm_b);

    // 3. latent = hs @ basis^T : [8192,64]
    gemm_nt<<<dim3(1, M / 128, 1), 256, 0, stream>>>(
        hs_b, basis_b, nullptr, nullptr, lat_b, M, R, C, 1, 0, 1, 0, 0, 0);

    // 4. vT = (hs @ v_w^T + v_b)^T : [B,H,64,T] bf16
    gemm_nt<<<dim3(C / 64, M / 128, 1), 256, 0, stream>>>(
        hs_b, vw_b, v_b, nullptr, vT_b, M, C, C, 1, 0, 1, 0, 0, 1);

    // 5. lt[b,h] = latent[b] @ hmT[h]^T : batched z = b*H+h
    gemm_nt<<<dim3(1, T / 128, B * H), 256, 0, stream>>>(
        lat_b, hm_b, nullptr, nullptr, lt_b, T, R, R,
        H, (long long)T * R, H, (long long)R * R, (long long)T * R, 0);

    // 6. flash attention v2 -> y bf16 [B,T,C]
    attn_kernel<<<dim3(8, H, B), 256, 0, stream>>>(lt_b, lat_b, vT_b, y_b);

    // 7. out = y @ o_w^T + o_b : f32
    gemm_nt<<<dim3(C / 64, M / 128, 1), 256, 0, stream>>>(
        y_b, ow_b, o_b, out, nullptr, M, C, C, 1, 0, 1, 0, 0, 0);
}